// Round 1
// baseline (147.207 us; speedup 1.0000x reference)
//
#include <hip/hip_runtime.h>

#define IN_H 1024
#define IN_W 1024
#define OUT_H 256
#define OUT_W 256
#define G 4              // output rows per block
#define ROWS (4*G + 12)  // 28 input rows touched per block (16-tap, stride 4, +halo)

// 16-tap antialiased bicubic weights for scale=0.25 (exact dyadic values,
// identical for every output position; sum == 1.0 exactly).
// W[j] = 0.25 * cubic((7.5 - j) * 0.25)
__constant__ float WTAP[16] = {
    -0.001708984375f, -0.010986328125f, -0.018310546875f, -0.011962890625f,
     0.022705078125f,  0.097412109375f,  0.181884765625f,  0.240966796875f,
     0.240966796875f,  0.181884765625f,  0.097412109375f,  0.022705078125f,
    -0.011962890625f, -0.018310546875f, -0.010986328125f, -0.001708984375f
};

// addr swizzle: insert one pad word every 8 words so a stride-4 gather maps
// to ~2-way bank aliasing (free) instead of 8-way (2.94x). A 16B-aligned
// quad [4t..4t+3] never crosses a pad boundary (4t % 8 in {0,4}).
#define SWZ(x) ((x) + ((x) >> 3))
#define LDS_ROW (IN_W + IN_W / 8)  // 1152 words

__global__ __launch_bounds__(256)
void bicubic_fused_kernel(const float* __restrict__ in, float* __restrict__ out) {
    const int t   = threadIdx.x;              // 0..255
    const int bc  = blockIdx.x / (OUT_H / G); // image index 0..23
    const int og  = blockIdx.x % (OUT_H / G); // output-row group
    const int oh0 = og * G;

    __shared__ float vrow[G][LDS_ROW];

    const float* src = in + (size_t)bc * IN_H * IN_W;

    // ---- vertical pass: 16-tap decimating conv along H, float4 per thread ----
    float4 acc[G];
#pragma unroll
    for (int i = 0; i < G; ++i) acc[i] = make_float4(0.f, 0.f, 0.f, 0.f);

#pragma unroll
    for (int r = 0; r < ROWS; ++r) {
        int y = oh0 * 4 + r - 6;
        y = min(max(y, 0), IN_H - 1);  // border replication
        const float4 v = *(const float4*)(src + (size_t)y * IN_W + 4 * t);
#pragma unroll
        for (int i = 0; i < G; ++i) {
            const int j = r - 4 * i;   // compile-time after unroll
            if (j >= 0 && j < 16) {
                const float w = WTAP[j];
                acc[i].x = fmaf(w, v.x, acc[i].x);
                acc[i].y = fmaf(w, v.y, acc[i].y);
                acc[i].z = fmaf(w, v.z, acc[i].z);
                acc[i].w = fmaf(w, v.w, acc[i].w);
            }
        }
    }

    // stage vertical results to swizzled LDS
    {
        const int x0 = 4 * t;
        const int a0 = SWZ(x0);
#pragma unroll
        for (int i = 0; i < G; ++i) {
            vrow[i][a0 + 0] = acc[i].x;
            vrow[i][a0 + 1] = acc[i].y;
            vrow[i][a0 + 2] = acc[i].z;
            vrow[i][a0 + 3] = acc[i].w;
        }
    }
    __syncthreads();

    // ---- horizontal pass: 16-tap decimating conv along W from LDS ----
#pragma unroll
    for (int i = 0; i < G; ++i) {
        float s = 0.f;
#pragma unroll
        for (int j = 0; j < 16; ++j) {
            int x = 4 * t + j - 6;
            x = min(max(x, 0), IN_W - 1);
            s = fmaf(WTAP[j], vrow[i][SWZ(x)], s);
        }
        out[((size_t)bc * OUT_H + oh0 + i) * OUT_W + t] = s;
    }
}

extern "C" void kernel_launch(void* const* d_in, const int* in_sizes, int n_in,
                              void* d_out, int out_size, void* d_ws, size_t ws_size,
                              hipStream_t stream) {
    const float* in = (const float*)d_in[0];
    float* out = (float*)d_out;
    const int nbc = in_sizes[0] / (IN_H * IN_W);  // 8*3 = 24
    dim3 grid(nbc * (OUT_H / G));                 // 24 * 64 = 1536 blocks
    dim3 block(256);
    bicubic_fused_kernel<<<grid, block, 0, stream>>>(in, out);
}

// Round 2
// 146.827 us; speedup vs baseline: 1.0026x; 1.0026x over previous
//
#include <hip/hip_runtime.h>

#define IN_H 1024
#define IN_W 1024
#define OUT_H 256
#define OUT_W 256
#define G 8                 // output rows per block
#define ROWS (4*G + 12)     // 44 input rows touched per block
#define GUARD_L 6
#define PITCH 1040          // 6 guard + 1024 data + 10 guard (multiple of 4 -> aligned rows)

// 16-tap antialiased bicubic weights for scale=0.25 (exact dyadic values,
// identical for every output position; sum == 1.0 exactly).
// W[j] = 0.25 * cubic((7.5 - j) * 0.25)
__constant__ float WTAP[16] = {
    -0.001708984375f, -0.010986328125f, -0.018310546875f, -0.011962890625f,
     0.022705078125f,  0.097412109375f,  0.181884765625f,  0.240966796875f,
     0.240966796875f,  0.181884765625f,  0.097412109375f,  0.022705078125f,
    -0.011962890625f, -0.018310546875f, -0.010986328125f, -0.001708984375f
};

__global__ __launch_bounds__(256, 3)
void bicubic_fused_kernel(const float* __restrict__ in, float* __restrict__ out) {
    const int t   = threadIdx.x;              // 0..255
    const int bc  = blockIdx.x / (OUT_H / G); // image index 0..23
    const int og  = blockIdx.x % (OUT_H / G); // output-row group
    const int oh0 = og * G;

    // Each LDS row: word index = x + GUARD_L for x in [0,1024); guards hold
    // replicated border values so the horizontal 16-tap window for output t
    // is exactly words [4t, 4t+16) -> four 16B-aligned float4 reads.
    __shared__ float vrow[G][PITCH];

    const float* src = in + (size_t)bc * IN_H * IN_W;

    // ---- vertical pass: 16-tap decimating conv along H, float4 per thread ----
    float4 acc[G];
#pragma unroll
    for (int i = 0; i < G; ++i) acc[i] = make_float4(0.f, 0.f, 0.f, 0.f);

#pragma unroll
    for (int r = 0; r < ROWS; ++r) {
        int y = oh0 * 4 + r - 6;
        y = min(max(y, 0), IN_H - 1);  // border replication
        const float4 v = *(const float4*)(src + (size_t)y * IN_W + 4 * t);
#pragma unroll
        for (int i = 0; i < G; ++i) {
            const int j = r - 4 * i;   // compile-time after unroll
            if (j >= 0 && j < 16) {
                const float w = WTAP[j];
                acc[i].x = fmaf(w, v.x, acc[i].x);
                acc[i].y = fmaf(w, v.y, acc[i].y);
                acc[i].z = fmaf(w, v.z, acc[i].z);
                acc[i].w = fmaf(w, v.w, acc[i].w);
            }
        }
    }

    // stage vertical results to LDS (main data at word 6+4t: 8B-aligned float2 pair)
#pragma unroll
    for (int i = 0; i < G; ++i) {
        float2* p = (float2*)&vrow[i][GUARD_L + 4 * t];
        p[0] = make_float2(acc[i].x, acc[i].y);
        p[1] = make_float2(acc[i].z, acc[i].w);
    }
    if (t == 0) {
#pragma unroll
        for (int i = 0; i < G; ++i)
            for (int k = 0; k < GUARD_L; ++k) vrow[i][k] = acc[i].x;   // x<0 -> v[0]
    }
    if (t == 255) {
#pragma unroll
        for (int i = 0; i < G; ++i)
            for (int k = GUARD_L + IN_W; k < PITCH; ++k) vrow[i][k] = acc[i].w; // x>1023 -> v[1023]
    }
    __syncthreads();

    // ---- horizontal pass: 4 aligned float4 LDS reads + 16 FMAs per output ----
#pragma unroll
    for (int i = 0; i < G; ++i) {
        const float4* q = (const float4*)&vrow[i][4 * t];  // 16B-aligned
        float s = 0.f;
#pragma unroll
        for (int k = 0; k < 4; ++k) {
            const float4 v = q[k];
            s = fmaf(WTAP[4 * k + 0], v.x, s);
            s = fmaf(WTAP[4 * k + 1], v.y, s);
            s = fmaf(WTAP[4 * k + 2], v.z, s);
            s = fmaf(WTAP[4 * k + 3], v.w, s);
        }
        out[((size_t)bc * OUT_H + oh0 + i) * OUT_W + t] = s;
    }
}

extern "C" void kernel_launch(void* const* d_in, const int* in_sizes, int n_in,
                              void* d_out, int out_size, void* d_ws, size_t ws_size,
                              hipStream_t stream) {
    const float* in = (const float*)d_in[0];
    float* out = (float*)d_out;
    const int nbc = in_sizes[0] / (IN_H * IN_W);   // 8*3 = 24
    dim3 grid(nbc * (OUT_H / G));                  // 24 * 32 = 768 blocks
    dim3 block(256);
    bicubic_fused_kernel<<<grid, block, 0, stream>>>(in, out);
}